// Round 1
// baseline (363.066 us; speedup 1.0000x reference)
//
#include <hip/hip_runtime.h>
#include <hip/hip_bf16.h>

// ---------- common types ----------
typedef __attribute__((ext_vector_type(8))) short bf16x8;
typedef __attribute__((ext_vector_type(4))) float f32x4;

__device__ __forceinline__ ushort f2bf(float f) {
  unsigned int u = __float_as_uint(f);
  u += 0x7fffu + ((u >> 16) & 1u);   // RNE
  return (ushort)(u >> 16);
}

__device__ __forceinline__ void gl_lds16(const void* g, void* l) {
  __builtin_amdgcn_global_load_lds(
      (const __attribute__((address_space(1))) void*)g,
      (__attribute__((address_space(3))) void*)l, 16, 0, 0);
}

// ---------- weight convert+transpose: W[K][N] f32 -> Wt[N][K] bf16 ----------
__global__ __launch_bounds__(256) void transpose_w(
    const float* __restrict__ W, ushort* __restrict__ Wt, int K, int N) {
  __shared__ float tile[32][33];
  const int tx = threadIdx.x, ty = threadIdx.y;  // (32, 8)
  const int bx = blockIdx.x, by = blockIdx.y;
#pragma unroll
  for (int j = 0; j < 4; j++)
    tile[ty + j * 8][tx] = W[(size_t)(by * 32 + ty + j * 8) * N + bx * 32 + tx];
  __syncthreads();
#pragma unroll
  for (int j = 0; j < 4; j++)
    Wt[(size_t)(bx * 32 + ty + j * 8) * K + by * 32 + tx] =
        f2bf(tile[tx][ty + j * 8]);
}

// ---------- layernorm: f32 row(1024) -> bf16 ----------
__global__ __launch_bounds__(256) void ln_bf16(
    const float* __restrict__ x, const float* __restrict__ g,
    const float* __restrict__ b, ushort* __restrict__ out) {
  const int row = blockIdx.x;
  const int t = threadIdx.x;
  float4 v = ((const float4*)(x + (size_t)row * 1024))[t];
  float s = v.x + v.y + v.z + v.w;
  float ss = v.x * v.x + v.y * v.y + v.z * v.z + v.w * v.w;
#pragma unroll
  for (int msk = 1; msk < 64; msk <<= 1) {
    s += __shfl_xor(s, msk);
    ss += __shfl_xor(ss, msk);
  }
  __shared__ float red[8];
  const int wv = t >> 6, ln = t & 63;
  if (ln == 0) { red[wv * 2] = s; red[wv * 2 + 1] = ss; }
  __syncthreads();
  s = red[0] + red[2] + red[4] + red[6];
  ss = red[1] + red[3] + red[5] + red[7];
  const float mu = s * (1.0f / 1024.0f);
  const float var = ss * (1.0f / 1024.0f) - mu * mu;
  const float rstd = rsqrtf(var + 1e-5f);
  float4 gv = ((const float4*)g)[t];
  float4 bv = ((const float4*)b)[t];
  ushort4 o;
  o.x = f2bf((v.x - mu) * rstd * gv.x + bv.x);
  o.y = f2bf((v.y - mu) * rstd * gv.y + bv.y);
  o.z = f2bf((v.z - mu) * rstd * gv.z + bv.z);
  o.w = f2bf((v.w - mu) * rstd * gv.w + bv.w);
  ((ushort4*)(out + (size_t)row * 1024))[t] = o;
}

// ---------- GEMM: C[M][N] = A[M][K](bf16) * Bt[N][K]^T(bf16) + bias, epilogue ----------
// EPI 0: bias -> bf16 out.  EPI 1: bias+GELU(exact) -> bf16 out.
// EPI 2: bias + resid(f32) -> f32 out.
template <int EPI>
__global__ __launch_bounds__(256) void gemm_bt(
    const ushort* __restrict__ A, const ushort* __restrict__ Bt,
    const float* __restrict__ bias, const float* __restrict__ resid,
    void* __restrict__ outp, int M, int N, int K) {
  __shared__ ushort sA[128 * 32];
  __shared__ ushort sB[128 * 32];
  const int t = threadIdx.x;
  const int lane = t & 63, wv = t >> 6;
  const int lr = lane & 15, lc = lane >> 4;
  const int m0 = blockIdx.y * 128, n0 = blockIdx.x * 128;
  const int wr = (wv >> 1) * 64, wc = (wv & 1) * 64;
  const int ch = t & 3;

  f32x4 acc[4][4];
#pragma unroll
  for (int m = 0; m < 4; m++)
#pragma unroll
    for (int n = 0; n < 4; n++) acc[m][n] = (f32x4){0.f, 0.f, 0.f, 0.f};

  for (int k0 = 0; k0 < K; k0 += 32) {
    __syncthreads();
#pragma unroll
    for (int s = 0; s < 2; s++) {
      const int r2 = (s * 256 + t) >> 2;
      gl_lds16(A + (size_t)(m0 + r2) * K + k0 + ch * 8, sA + s * 2048 + wv * 512);
      gl_lds16(Bt + (size_t)(n0 + r2) * K + k0 + ch * 8, sB + s * 2048 + wv * 512);
    }
    __syncthreads();
    bf16x8 af[4], bfr[4];
#pragma unroll
    for (int m = 0; m < 4; m++)
      af[m] = *(const bf16x8*)&sA[(wr + m * 16 + lr) * 32 + lc * 8];
#pragma unroll
    for (int n = 0; n < 4; n++)
      bfr[n] = *(const bf16x8*)&sB[(wc + n * 16 + lr) * 32 + lc * 8];
#pragma unroll
    for (int m = 0; m < 4; m++)
#pragma unroll
      for (int n = 0; n < 4; n++)
        acc[m][n] = __builtin_amdgcn_mfma_f32_16x16x32_bf16(af[m], bfr[n],
                                                            acc[m][n], 0, 0, 0);
  }

#pragma unroll
  for (int m = 0; m < 4; m++) {
#pragma unroll
    for (int n = 0; n < 4; n++) {
      const int gr0 = m0 + wr + m * 16 + lc * 4;
      const int gc = n0 + wc + n * 16 + lr;
      const float bs = bias[gc];
#pragma unroll
      for (int r = 0; r < 4; r++) {
        const float v = acc[m][n][r] + bs;
        const int gr = gr0 + r;
        if (EPI == 0) {
          ((ushort*)outp)[(size_t)gr * N + gc] = f2bf(v);
        } else if (EPI == 1) {
          const float gg = 0.5f * v * (1.0f + erff(v * 0.70710678118654752f));
          ((ushort*)outp)[(size_t)gr * N + gc] = f2bf(gg);
        } else {
          ((float*)outp)[(size_t)gr * N + gc] =
              v + resid[(size_t)gr * N + gc];
        }
      }
    }
  }
}

// ---------- flash attention ----------
// qkv bf16 [4096][3072]: q at col h*64+d, k at 1024+h*64+d, v at 2048+h*64+d
// grid (16 qblocks, 64 bh); 256 threads = 4 waves; wave handles 16 q rows.
__global__ __launch_bounds__(256) void attn_kernel(
    const ushort* __restrict__ qkv, ushort* __restrict__ o_out) {
  __shared__ ushort sK[32 * 72];     // [key][d] padded
  __shared__ ushort sVt[64 * 40];    // [d][kv] padded
  __shared__ ushort sP[4 * 16 * 40]; // per-wave [qrow][kv] padded
  const int t = threadIdx.x;
  const int lane = t & 63, wid = t >> 6;
  const int lr = lane & 15, lc = lane >> 4;
  const int qb = blockIdx.x;       // 0..15
  const int bh = blockIdx.y;       // 0..63
  const int bidx = bh >> 4, h = bh & 15;
  const size_t base = (size_t)bidx * 1024 * 3072;
  const int q0 = qb * 64;
  const int qrow = q0 + wid * 16 + lr;

  bf16x8 qf[2];
  qf[0] = *(const bf16x8*)&qkv[base + (size_t)qrow * 3072 + h * 64 + lc * 8];
  qf[1] = *(const bf16x8*)&qkv[base + (size_t)qrow * 3072 + h * 64 + 32 + lc * 8];

  f32x4 o_acc[4];
#pragma unroll
  for (int n = 0; n < 4; n++) o_acc[n] = (f32x4){0.f, 0.f, 0.f, 0.f};
  float m_r[4] = {-1e30f, -1e30f, -1e30f, -1e30f};
  float l_r[4] = {0.f, 0.f, 0.f, 0.f};

  const int krow = t >> 3, kch = t & 7;
  ushort* pw = sP + wid * 640;

  for (int kv0 = 0; kv0 < 1024; kv0 += 32) {
    __syncthreads();
    // K tile [32][64] -> sK
    uint4 kd = *(const uint4*)&qkv[base + (size_t)(kv0 + krow) * 3072 + 1024 +
                                   h * 64 + kch * 8];
    *(uint4*)&sK[krow * 72 + kch * 8] = kd;
    // V tile transposed -> sVt[d][kv]
    uint4 vd = *(const uint4*)&qkv[base + (size_t)(kv0 + krow) * 3072 + 2048 +
                                   h * 64 + kch * 8];
    union { uint4 u; ushort s[8]; } vv;
    vv.u = vd;
#pragma unroll
    for (int j = 0; j < 8; j++) sVt[(kch * 8 + j) * 40 + krow] = vv.s[j];
    __syncthreads();

    // S = Q K^T  (two 16x16 blocks: keys 0-15, 16-31)
    f32x4 s0 = (f32x4){0.f, 0.f, 0.f, 0.f};
    f32x4 s1 = (f32x4){0.f, 0.f, 0.f, 0.f};
    bf16x8 kf;
    kf = *(const bf16x8*)&sK[(0 + lr) * 72 + 0 + lc * 8];
    s0 = __builtin_amdgcn_mfma_f32_16x16x32_bf16(qf[0], kf, s0, 0, 0, 0);
    kf = *(const bf16x8*)&sK[(0 + lr) * 72 + 32 + lc * 8];
    s0 = __builtin_amdgcn_mfma_f32_16x16x32_bf16(qf[1], kf, s0, 0, 0, 0);
    kf = *(const bf16x8*)&sK[(16 + lr) * 72 + 0 + lc * 8];
    s1 = __builtin_amdgcn_mfma_f32_16x16x32_bf16(qf[0], kf, s1, 0, 0, 0);
    kf = *(const bf16x8*)&sK[(16 + lr) * 72 + 32 + lc * 8];
    s1 = __builtin_amdgcn_mfma_f32_16x16x32_bf16(qf[1], kf, s1, 0, 0, 0);

    // online softmax (lane holds rows lc*4+r, col lr / lr+16)
    float mt[4], p0[4], p1[4], alpha[4], rowsum[4];
#pragma unroll
    for (int r = 0; r < 4; r++) {
      s0[r] *= 0.125f;
      s1[r] *= 0.125f;
      mt[r] = fmaxf(s0[r], s1[r]);
    }
#pragma unroll
    for (int msk = 1; msk < 16; msk <<= 1)
#pragma unroll
      for (int r = 0; r < 4; r++) mt[r] = fmaxf(mt[r], __shfl_xor(mt[r], msk));
#pragma unroll
    for (int r = 0; r < 4; r++) {
      const float mn = fmaxf(m_r[r], mt[r]);
      alpha[r] = __expf(m_r[r] - mn);
      m_r[r] = mn;
      p0[r] = __expf(s0[r] - mn);
      p1[r] = __expf(s1[r] - mn);
      rowsum[r] = p0[r] + p1[r];
    }
#pragma unroll
    for (int msk = 1; msk < 16; msk <<= 1)
#pragma unroll
      for (int r = 0; r < 4; r++) rowsum[r] += __shfl_xor(rowsum[r], msk);
#pragma unroll
    for (int r = 0; r < 4; r++) {
      l_r[r] = l_r[r] * alpha[r] + rowsum[r];
#pragma unroll
      for (int n = 0; n < 4; n++) o_acc[n][r] *= alpha[r];
    }
    // write P (bf16) to per-wave LDS
#pragma unroll
    for (int r = 0; r < 4; r++) {
      pw[(lc * 4 + r) * 40 + lr] = f2bf(p0[r]);
      pw[(lc * 4 + r) * 40 + 16 + lr] = f2bf(p1[r]);
    }
    __syncthreads();

    // O += P V
    bf16x8 af = *(const bf16x8*)&pw[lr * 40 + lc * 8];
#pragma unroll
    for (int n = 0; n < 4; n++) {
      bf16x8 vf = *(const bf16x8*)&sVt[(n * 16 + lr) * 40 + lc * 8];
      o_acc[n] = __builtin_amdgcn_mfma_f32_16x16x32_bf16(af, vf, o_acc[n], 0, 0, 0);
    }
  }

  // normalize + write o[b,n,h,d] bf16 [4096][1024]
#pragma unroll
  for (int n = 0; n < 4; n++)
#pragma unroll
    for (int r = 0; r < 4; r++) {
      const int row = q0 + wid * 16 + lc * 4 + r;
      const int col = h * 64 + n * 16 + lr;
      o_out[(size_t)(bidx * 1024 + row) * 1024 + col] =
          f2bf(o_acc[n][r] / l_r[r]);
    }
}

// ---------- launch ----------
extern "C" void kernel_launch(void* const* d_in, const int* in_sizes, int n_in,
                              void* d_out, int out_size, void* d_ws,
                              size_t ws_size, hipStream_t stream) {
  const float* x      = (const float*)d_in[0];
  const float* ln1_g  = (const float*)d_in[1];
  const float* ln1_b  = (const float*)d_in[2];
  const float* w_qkv  = (const float*)d_in[3];
  const float* b_qkv  = (const float*)d_in[4];
  const float* w_proj = (const float*)d_in[5];
  const float* b_proj = (const float*)d_in[6];
  const float* ln2_g  = (const float*)d_in[7];
  const float* ln2_b  = (const float*)d_in[8];
  const float* w_fc1  = (const float*)d_in[9];
  const float* b_fc1  = (const float*)d_in[10];
  const float* w_fc2  = (const float*)d_in[11];
  const float* b_fc2  = (const float*)d_in[12];
  float* out = (float*)d_out;

  ushort* ws      = (ushort*)d_ws;
  ushort* wt_qkv  = ws;                         // 3072*1024
  ushort* wt_proj = wt_qkv + 3072 * 1024;       // 1024*1024
  ushort* wt_fc1  = wt_proj + 1024 * 1024;      // 4096*1024
  ushort* wt_fc2  = wt_fc1 + 4096 * 1024;       // 1024*4096
  ushort* hbuf    = wt_fc2 + 1024 * 4096;       // 4096*1024
  ushort* qkv     = hbuf + 4096 * 1024;         // 4096*3072
  ushort* obuf    = qkv + 4096 * 3072;          // 4096*1024
  ushort* h3      = qkv;                        // aliases qkv+obuf (4096*4096)

  // weight transposes (f32 -> bf16, [K][N] -> [N][K])
  transpose_w<<<dim3(96, 32), dim3(32, 8), 0, stream>>>(w_qkv, wt_qkv, 1024, 3072);
  transpose_w<<<dim3(32, 32), dim3(32, 8), 0, stream>>>(w_proj, wt_proj, 1024, 1024);
  transpose_w<<<dim3(128, 32), dim3(32, 8), 0, stream>>>(w_fc1, wt_fc1, 1024, 4096);
  transpose_w<<<dim3(32, 128), dim3(32, 8), 0, stream>>>(w_fc2, wt_fc2, 4096, 1024);

  // LN1
  ln_bf16<<<4096, 256, 0, stream>>>(x, ln1_g, ln1_b, hbuf);
  // QKV
  gemm_bt<0><<<dim3(24, 32), 256, 0, stream>>>(hbuf, wt_qkv, b_qkv, nullptr,
                                               qkv, 4096, 3072, 1024);
  // attention
  attn_kernel<<<dim3(16, 64), 256, 0, stream>>>(qkv, obuf);
  // proj + residual -> x1 (f32, in d_out)
  gemm_bt<2><<<dim3(8, 32), 256, 0, stream>>>(obuf, wt_proj, b_proj, x, out,
                                              4096, 1024, 1024);
  // LN2
  ln_bf16<<<4096, 256, 0, stream>>>(out, ln2_g, ln2_b, hbuf);
  // fc1 + GELU
  gemm_bt<1><<<dim3(32, 32), 256, 0, stream>>>(hbuf, wt_fc1, b_fc1, nullptr,
                                               h3, 4096, 4096, 1024);
  // fc2 + residual -> out
  gemm_bt<2><<<dim3(8, 32), 256, 0, stream>>>(h3, wt_fc2, b_fc2, out, out,
                                              4096, 1024, 4096);
}

// Round 2
// 305.701 us; speedup vs baseline: 1.1877x; 1.1877x over previous
//
#include <hip/hip_runtime.h>
#include <hip/hip_bf16.h>

// ---------- common types ----------
typedef __attribute__((ext_vector_type(8))) short bf16x8;
typedef __attribute__((ext_vector_type(4))) float f32x4;

__device__ __forceinline__ ushort f2bf(float f) {
  unsigned int u = __float_as_uint(f);
  u += 0x7fffu + ((u >> 16) & 1u);   // RNE
  return (ushort)(u >> 16);
}

__device__ __forceinline__ void gl_lds16(const void* g, void* l) {
  __builtin_amdgcn_global_load_lds(
      (const __attribute__((address_space(1))) void*)g,
      (__attribute__((address_space(3))) void*)l, 16, 0, 0);
}

// ---------- weight convert+transpose: W[K][N] f32 -> Wt[N][K] bf16 ----------
__global__ __launch_bounds__(256) void transpose_w(
    const float* __restrict__ W, ushort* __restrict__ Wt, int K, int N) {
  __shared__ float tile[32][33];
  const int tx = threadIdx.x, ty = threadIdx.y;  // (32, 8)
  const int bx = blockIdx.x, by = blockIdx.y;
#pragma unroll
  for (int j = 0; j < 4; j++)
    tile[ty + j * 8][tx] = W[(size_t)(by * 32 + ty + j * 8) * N + bx * 32 + tx];
  __syncthreads();
#pragma unroll
  for (int j = 0; j < 4; j++)
    Wt[(size_t)(bx * 32 + ty + j * 8) * K + by * 32 + tx] =
        f2bf(tile[tx][ty + j * 8]);
}

// ---------- V transpose: qkv V-part -> vt[bh][d][n] bf16 ----------
__global__ __launch_bounds__(256) void transpose_v(
    const ushort* __restrict__ qkv, ushort* __restrict__ vt) {
  __shared__ ushort tile[32][33];
  const int tx = threadIdx.x, ty = threadIdx.y;  // (32, 8)
  const int n0 = blockIdx.x * 32;   // token tile
  const int d0 = blockIdx.y * 32;   // d tile (0 or 32)
  const int bh = blockIdx.z;        // 0..63
  const int bidx = bh >> 4, h = bh & 15;
#pragma unroll
  for (int j = 0; j < 4; j++)
    tile[ty + j * 8][tx] =
        qkv[(size_t)(bidx * 1024 + n0 + ty + j * 8) * 3072 + 2048 + h * 64 +
            d0 + tx];
  __syncthreads();
#pragma unroll
  for (int j = 0; j < 4; j++)
    vt[(size_t)(bh * 64 + d0 + ty + j * 8) * 1024 + n0 + tx] =
        tile[tx][ty + j * 8];
}

// ---------- layernorm: f32 row(1024) -> bf16 ----------
__global__ __launch_bounds__(256) void ln_bf16(
    const float* __restrict__ x, const float* __restrict__ g,
    const float* __restrict__ b, ushort* __restrict__ out) {
  const int row = blockIdx.x;
  const int t = threadIdx.x;
  float4 v = ((const float4*)(x + (size_t)row * 1024))[t];
  float s = v.x + v.y + v.z + v.w;
  float ss = v.x * v.x + v.y * v.y + v.z * v.z + v.w * v.w;
#pragma unroll
  for (int msk = 1; msk < 64; msk <<= 1) {
    s += __shfl_xor(s, msk);
    ss += __shfl_xor(ss, msk);
  }
  __shared__ float red[8];
  const int wv = t >> 6, ln = t & 63;
  if (ln == 0) { red[wv * 2] = s; red[wv * 2 + 1] = ss; }
  __syncthreads();
  s = red[0] + red[2] + red[4] + red[6];
  ss = red[1] + red[3] + red[5] + red[7];
  const float mu = s * (1.0f / 1024.0f);
  const float var = ss * (1.0f / 1024.0f) - mu * mu;
  const float rstd = rsqrtf(var + 1e-5f);
  float4 gv = ((const float4*)g)[t];
  float4 bv = ((const float4*)b)[t];
  ushort4 o;
  o.x = f2bf((v.x - mu) * rstd * gv.x + bv.x);
  o.y = f2bf((v.y - mu) * rstd * gv.y + bv.y);
  o.z = f2bf((v.z - mu) * rstd * gv.z + bv.z);
  o.w = f2bf((v.w - mu) * rstd * gv.w + bv.w);
  ((ushort4*)(out + (size_t)row * 1024))[t] = o;
}

// ---------- GEMM: C[M][N] = A[M][K](bf16) * Bt[N][K]^T(bf16) + bias ----------
// EPI 0: bias -> bf16. EPI 1: bias+GELU -> bf16. EPI 2: bias+resid -> f32.
template <int EPI>
__global__ __launch_bounds__(256) void gemm_bt(
    const ushort* __restrict__ A, const ushort* __restrict__ Bt,
    const float* __restrict__ bias, const float* __restrict__ resid,
    void* __restrict__ outp, int M, int N, int K) {
  __shared__ ushort sA[128 * 32];
  __shared__ ushort sB[128 * 32];
  const int t = threadIdx.x;
  const int lane = t & 63, wv = t >> 6;
  const int lr = lane & 15, lc = lane >> 4;
  const int m0 = blockIdx.y * 128, n0 = blockIdx.x * 128;
  const int wr = (wv >> 1) * 64, wc = (wv & 1) * 64;
  const int ch = t & 3;

  f32x4 acc[4][4];
#pragma unroll
  for (int m = 0; m < 4; m++)
#pragma unroll
    for (int n = 0; n < 4; n++) acc[m][n] = (f32x4){0.f, 0.f, 0.f, 0.f};

  for (int k0 = 0; k0 < K; k0 += 32) {
    __syncthreads();
#pragma unroll
    for (int s = 0; s < 2; s++) {
      const int r2 = (s * 256 + t) >> 2;
      gl_lds16(A + (size_t)(m0 + r2) * K + k0 + ch * 8, sA + s * 2048 + wv * 512);
      gl_lds16(Bt + (size_t)(n0 + r2) * K + k0 + ch * 8, sB + s * 2048 + wv * 512);
    }
    __syncthreads();
    bf16x8 af[4], bfr[4];
#pragma unroll
    for (int m = 0; m < 4; m++)
      af[m] = *(const bf16x8*)&sA[(wr + m * 16 + lr) * 32 + lc * 8];
#pragma unroll
    for (int n = 0; n < 4; n++)
      bfr[n] = *(const bf16x8*)&sB[(wc + n * 16 + lr) * 32 + lc * 8];
#pragma unroll
    for (int m = 0; m < 4; m++)
#pragma unroll
      for (int n = 0; n < 4; n++)
        acc[m][n] = __builtin_amdgcn_mfma_f32_16x16x32_bf16(af[m], bfr[n],
                                                            acc[m][n], 0, 0, 0);
  }

#pragma unroll
  for (int m = 0; m < 4; m++) {
#pragma unroll
    for (int n = 0; n < 4; n++) {
      const int gr0 = m0 + wr + m * 16 + lc * 4;
      const int gc = n0 + wc + n * 16 + lr;
      const float bs = bias[gc];
#pragma unroll
      for (int r = 0; r < 4; r++) {
        const float v = acc[m][n][r] + bs;
        const int gr = gr0 + r;
        if (EPI == 0) {
          ((ushort*)outp)[(size_t)gr * N + gc] = f2bf(v);
        } else if (EPI == 1) {
          const float gg = 0.5f * v * (1.0f + erff(v * 0.70710678118654752f));
          ((ushort*)outp)[(size_t)gr * N + gc] = f2bf(gg);
        } else {
          ((float*)outp)[(size_t)gr * N + gc] =
              v + resid[(size_t)gr * N + gc];
        }
      }
    }
  }
}

// ---------- flash attention v2 (swapped operands) ----------
// grid (8 qtiles, 64 bh); 256 threads = 4 waves; wave owns 32 q rows.
// KVBLK=64. S^T = mfma(K, Q); O^T = mfma(V^T, P).
__global__ __launch_bounds__(256) void attn_kernel(
    const ushort* __restrict__ qkv, const ushort* __restrict__ vt,
    ushort* __restrict__ o_out) {
  __shared__ ushort sK[4096];        // [dh2][key64][32]
  __shared__ ushort sV[4096];        // [kvh2][d64][32]   (V^T tile)
  __shared__ ushort sP[4 * 32 * 72]; // per-wave P[q32][kv64] pad 72
  const int t = threadIdx.x;
  const int lane = t & 63, wid = t >> 6;
  const int lr = lane & 15, lc = lane >> 4;
  const int qb = blockIdx.x;   // 0..7
  const int bh = blockIdx.y;   // 0..63
  const int bidx = bh >> 4, h = bh & 15;
  const size_t base = (size_t)bidx * 1024 * 3072;
  const int q0w = qb * 128 + wid * 32;

  // Q as B-operand fragments: row(q)=lr+nf*16, k(d)=kd*32+lc*8
  bf16x8 qf[2][2];
#pragma unroll
  for (int nf = 0; nf < 2; nf++)
#pragma unroll
    for (int kd = 0; kd < 2; kd++)
      qf[nf][kd] = *(const bf16x8*)&qkv[base +
          (size_t)(q0w + nf * 16 + lr) * 3072 + h * 64 + kd * 32 + lc * 8];

  f32x4 oacc[4][2];  // O^T: [d-frag][q-frag]
#pragma unroll
  for (int mf = 0; mf < 4; mf++)
#pragma unroll
    for (int nf = 0; nf < 2; nf++) oacc[mf][nf] = (f32x4){0.f, 0.f, 0.f, 0.f};
  float m_r[2] = {-1e30f, -1e30f};
  float l_r[2] = {0.f, 0.f};

  const int srow = lane >> 2;         // 0..15
  const int scol = (lane & 3) * 8;
  ushort* pw = sP + wid * 2304;

  for (int kv0 = 0; kv0 < 1024; kv0 += 64) {
    __syncthreads();
    // stage K [dh][key][32] and V^T [kvh][d][32] via async global->LDS
#pragma unroll
    for (int s = 0; s < 2; s++) {
      gl_lds16(qkv + base + (size_t)(kv0 + wid * 16 + srow) * 3072 + 1024 +
                   h * 64 + s * 32 + scol,
               sK + s * 2048 + wid * 512);
      gl_lds16(vt + (size_t)(bh * 64 + wid * 16 + srow) * 1024 + kv0 + s * 32 +
                   scol,
               sV + s * 2048 + wid * 512);
    }
    __syncthreads();

    // S^T[kv][q] = K · Q^T  (raw scores)
    f32x4 st[4][2];
#pragma unroll
    for (int mf = 0; mf < 4; mf++) {
      bf16x8 ka0 = *(const bf16x8*)&sK[(mf * 16 + lr) * 32 + lc * 8];
      bf16x8 ka1 = *(const bf16x8*)&sK[2048 + (mf * 16 + lr) * 32 + lc * 8];
#pragma unroll
      for (int nf = 0; nf < 2; nf++) {
        f32x4 z = (f32x4){0.f, 0.f, 0.f, 0.f};
        z = __builtin_amdgcn_mfma_f32_16x16x32_bf16(ka0, qf[nf][0], z, 0, 0, 0);
        z = __builtin_amdgcn_mfma_f32_16x16x32_bf16(ka1, qf[nf][1], z, 0, 0, 0);
        st[mf][nf] = z;
      }
    }

    // online softmax per q-column (col = lr + nf*16; kv spread over lc,reg,mf)
#pragma unroll
    for (int nf = 0; nf < 2; nf++) {
      float mx = st[0][nf][0];
#pragma unroll
      for (int mf = 0; mf < 4; mf++)
        mx = fmaxf(mx, fmaxf(fmaxf(st[mf][nf][0], st[mf][nf][1]),
                             fmaxf(st[mf][nf][2], st[mf][nf][3])));
      mx = fmaxf(mx, __shfl_xor(mx, 16));
      mx = fmaxf(mx, __shfl_xor(mx, 32));
      mx *= 0.125f;  // scale = Dh^-0.5
      const float mn = fmaxf(m_r[nf], mx);
      const float alpha = __expf(m_r[nf] - mn);
      m_r[nf] = mn;
      float rs = 0.f;
#pragma unroll
      for (int mf = 0; mf < 4; mf++) {
        const float p0 = __expf(fmaf(st[mf][nf][0], 0.125f, -mn));
        const float p1 = __expf(fmaf(st[mf][nf][1], 0.125f, -mn));
        const float p2 = __expf(fmaf(st[mf][nf][2], 0.125f, -mn));
        const float p3 = __expf(fmaf(st[mf][nf][3], 0.125f, -mn));
        rs += (p0 + p1) + (p2 + p3);
        uint2 u;
        u.x = (uint)f2bf(p0) | ((uint)f2bf(p1) << 16);
        u.y = (uint)f2bf(p2) | ((uint)f2bf(p3) << 16);
        // P[q = nf*16+lr][kv = mf*16 + lc*4 + r]
        *(uint2*)&pw[(nf * 16 + lr) * 72 + mf * 16 + lc * 4] = u;
      }
      rs += __shfl_xor(rs, 16);
      rs += __shfl_xor(rs, 32);
      l_r[nf] = l_r[nf] * alpha + rs;
#pragma unroll
      for (int mf = 0; mf < 4; mf++) {
        oacc[mf][nf][0] *= alpha;
        oacc[mf][nf][1] *= alpha;
        oacc[mf][nf][2] *= alpha;
        oacc[mf][nf][3] *= alpha;
      }
    }

    // O^T += V^T · P^T  (wave-local LDS RAW; no barrier needed)
#pragma unroll
    for (int ks = 0; ks < 2; ks++) {
      bf16x8 pb0 = *(const bf16x8*)&pw[lr * 72 + ks * 32 + lc * 8];
      bf16x8 pb1 = *(const bf16x8*)&pw[(16 + lr) * 72 + ks * 32 + lc * 8];
#pragma unroll
      for (int mf = 0; mf < 4; mf++) {
        bf16x8 va = *(const bf16x8*)&sV[ks * 2048 + (mf * 16 + lr) * 32 + lc * 8];
        oacc[mf][0] =
            __builtin_amdgcn_mfma_f32_16x16x32_bf16(va, pb0, oacc[mf][0], 0, 0, 0);
        oacc[mf][1] =
            __builtin_amdgcn_mfma_f32_16x16x32_bf16(va, pb1, oacc[mf][1], 0, 0, 0);
      }
    }
  }

  // epilogue: O[token][h*64+d] = O^T / l
  const float inv[2] = {1.f / l_r[0], 1.f / l_r[1]};
#pragma unroll
  for (int mf = 0; mf < 4; mf++)
#pragma unroll
    for (int nf = 0; nf < 2; nf++) {
      ushort4 o4;
      o4.x = f2bf(oacc[mf][nf][0] * inv[nf]);
      o4.y = f2bf(oacc[mf][nf][1] * inv[nf]);
      o4.z = f2bf(oacc[mf][nf][2] * inv[nf]);
      o4.w = f2bf(oacc[mf][nf][3] * inv[nf]);
      *(ushort4*)&o_out[(size_t)(bidx * 1024 + q0w + nf * 16 + lr) * 1024 +
                        h * 64 + mf * 16 + lc * 4] = o4;
    }
}

// ---------- launch ----------
extern "C" void kernel_launch(void* const* d_in, const int* in_sizes, int n_in,
                              void* d_out, int out_size, void* d_ws,
                              size_t ws_size, hipStream_t stream) {
  const float* x      = (const float*)d_in[0];
  const float* ln1_g  = (const float*)d_in[1];
  const float* ln1_b  = (const float*)d_in[2];
  const float* w_qkv  = (const float*)d_in[3];
  const float* b_qkv  = (const float*)d_in[4];
  const float* w_proj = (const float*)d_in[5];
  const float* b_proj = (const float*)d_in[6];
  const float* ln2_g  = (const float*)d_in[7];
  const float* ln2_b  = (const float*)d_in[8];
  const float* w_fc1  = (const float*)d_in[9];
  const float* b_fc1  = (const float*)d_in[10];
  const float* w_fc2  = (const float*)d_in[11];
  const float* b_fc2  = (const float*)d_in[12];
  float* out = (float*)d_out;

  ushort* ws      = (ushort*)d_ws;
  ushort* wt_qkv  = ws;                         // 3072*1024
  ushort* wt_proj = wt_qkv + 3072 * 1024;       // 1024*1024
  ushort* wt_fc1  = wt_proj + 1024 * 1024;      // 4096*1024
  ushort* wt_fc2  = wt_fc1 + 4096 * 1024;       // 1024*4096
  ushort* hbuf    = wt_fc2 + 1024 * 4096;       // 4096*1024
  ushort* qkv     = hbuf + 4096 * 1024;         // 4096*3072
  ushort* obuf    = qkv + 4096 * 3072;          // 4096*1024
  ushort* h3      = qkv;                        // aliases qkv+obuf (4096*4096)
  ushort* vtb     = hbuf;                       // vt[64][64][1024]; hbuf free
                                                // after QKV GEMM consumed it

  transpose_w<<<dim3(96, 32), dim3(32, 8), 0, stream>>>(w_qkv, wt_qkv, 1024, 3072);
  transpose_w<<<dim3(32, 32), dim3(32, 8), 0, stream>>>(w_proj, wt_proj, 1024, 1024);
  transpose_w<<<dim3(128, 32), dim3(32, 8), 0, stream>>>(w_fc1, wt_fc1, 1024, 4096);
  transpose_w<<<dim3(32, 128), dim3(32, 8), 0, stream>>>(w_fc2, wt_fc2, 4096, 1024);

  ln_bf16<<<4096, 256, 0, stream>>>(x, ln1_g, ln1_b, hbuf);
  gemm_bt<0><<<dim3(24, 32), 256, 0, stream>>>(hbuf, wt_qkv, b_qkv, nullptr,
                                               qkv, 4096, 3072, 1024);
  transpose_v<<<dim3(32, 2, 64), dim3(32, 8), 0, stream>>>(qkv, vtb);
  attn_kernel<<<dim3(8, 64), 256, 0, stream>>>(qkv, vtb, obuf);
  gemm_bt<2><<<dim3(8, 32), 256, 0, stream>>>(obuf, wt_proj, b_proj, x, out,
                                              4096, 1024, 1024);
  ln_bf16<<<4096, 256, 0, stream>>>(out, ln2_g, ln2_b, hbuf);
  gemm_bt<1><<<dim3(32, 32), 256, 0, stream>>>(hbuf, wt_fc1, b_fc1, nullptr,
                                               h3, 4096, 4096, 1024);
  gemm_bt<2><<<dim3(8, 32), 256, 0, stream>>>(h3, wt_fc2, b_fc2, out, out,
                                              4096, 1024, 4096);
}